// Round 1
// baseline (865.382 us; speedup 1.0000x reference)
//
#include <hip/hip_runtime.h>
#include <hip/hip_bf16.h>

typedef __attribute__((ext_vector_type(4))) float f32x4;
typedef __attribute__((ext_vector_type(8))) short s16x8;

#define B_      32
#define S_      128
#define SEQ     129
#define IN_DIM  1024
#define HD      1024
#define NHEAD   8
#define DH      128
#define OUT_DIM 256
#define KC      10
#define DFF     2048
#define MROWS   (B_*SEQ)     // 4128
#define NCAND   (B_*S_*KC)   // 40960

__device__ __forceinline__ short f2bf(float f) {
  unsigned u = __builtin_bit_cast(unsigned, f);
  u += 0x7FFFu + ((u >> 16) & 1u);   // RNE to bf16
  return (short)(u >> 16);
}

// ---------------- transpose + convert: W[K][N] f32 -> Wt[N][K] bf16 ----------
__global__ __launch_bounds__(256) void transpose_bf16(const float* __restrict__ W,
                                                      short* __restrict__ Wt,
                                                      int K, int N) {
  __shared__ float tile[32][33];
  const int n0 = blockIdx.x << 5, k0 = blockIdx.y << 5;
  const int tx = threadIdx.x & 31, ty = threadIdx.x >> 5;  // 32 x 8
#pragma unroll
  for (int i = 0; i < 4; ++i)
    tile[ty + i * 8][tx] = W[(size_t)(k0 + ty + i * 8) * N + n0 + tx];
  __syncthreads();
#pragma unroll
  for (int i = 0; i < 4; ++i)
    Wt[(size_t)(n0 + ty + i * 8) * K + k0 + tx] = f2bf(tile[tx][ty + i * 8]);
}

// ---------------- GEMM: C[M][N] = A[M][K](f32) * Bt[N][K](bf16) + bias; EPI=1 -> relu
template <int EPI>
__global__ __launch_bounds__(256) void gemm_bt(const float* __restrict__ A,
                                               const short* __restrict__ Bt,
                                               const float* __restrict__ bias,
                                               float* __restrict__ C,
                                               int M, int N, int K) {
  __shared__ alignas(16) short As[128][40];   // +8 pad: kills 8-way ds_read conflicts
  __shared__ alignas(16) short Bs[128][40];
  const int tid = threadIdx.x;
  const int lane = tid & 63, wave = tid >> 6;
  const int wr = wave >> 1, wc = wave & 1;          // 2x2 waves, 64x64 each
  const int bm = blockIdx.x * 128, bn = blockIdx.y * 128;
  const int r2 = tid >> 1, c2 = (tid & 1) << 4;     // staging: row, col0 (0/16)
  const int arow = bm + r2;
  const int lrow = lane & 15, lk = (lane >> 4) << 3;

  f32x4 acc[4][4] = {};

  for (int k0 = 0; k0 < K; k0 += 32) {
    s16x8 av0 = {0,0,0,0,0,0,0,0}, av1 = {0,0,0,0,0,0,0,0};
    if (arow < M) {
      const float* ap = A + (size_t)arow * K + k0 + c2;
      f32x4 v0 = *(const f32x4*)(ap + 0);
      f32x4 v1 = *(const f32x4*)(ap + 4);
      f32x4 v2 = *(const f32x4*)(ap + 8);
      f32x4 v3 = *(const f32x4*)(ap + 12);
      av0[0]=f2bf(v0.x); av0[1]=f2bf(v0.y); av0[2]=f2bf(v0.z); av0[3]=f2bf(v0.w);
      av0[4]=f2bf(v1.x); av0[5]=f2bf(v1.y); av0[6]=f2bf(v1.z); av0[7]=f2bf(v1.w);
      av1[0]=f2bf(v2.x); av1[1]=f2bf(v2.y); av1[2]=f2bf(v2.z); av1[3]=f2bf(v2.w);
      av1[4]=f2bf(v3.x); av1[5]=f2bf(v3.y); av1[6]=f2bf(v3.z); av1[7]=f2bf(v3.w);
    }
    const short* bp = Bt + (size_t)(bn + r2) * K + k0 + c2;  // N always %128==0
    s16x8 bv0 = *(const s16x8*)(bp);
    s16x8 bv1 = *(const s16x8*)(bp + 8);

    __syncthreads();
    *(s16x8*)&As[r2][c2]     = av0;
    *(s16x8*)&As[r2][c2 + 8] = av1;
    *(s16x8*)&Bs[r2][c2]     = bv0;
    *(s16x8*)&Bs[r2][c2 + 8] = bv1;
    __syncthreads();

    s16x8 af[4], bfr[4];
#pragma unroll
    for (int m = 0; m < 4; ++m)
      af[m] = *(const s16x8*)&As[wr * 64 + m * 16 + lrow][lk];
#pragma unroll
    for (int n = 0; n < 4; ++n)
      bfr[n] = *(const s16x8*)&Bs[wc * 64 + n * 16 + lrow][lk];
#pragma unroll
    for (int m = 0; m < 4; ++m)
#pragma unroll
      for (int n = 0; n < 4; ++n)
        asm("v_mfma_f32_16x16x32_bf16 %0, %1, %2, %0"
            : "+v"(acc[m][n]) : "v"(af[m]), "v"(bfr[n]));
  }

  const int lg4 = (lane >> 4) << 2;
#pragma unroll
  for (int n = 0; n < 4; ++n) {
    const int col = bn + wc * 64 + n * 16 + lrow;
    const float bv = bias[col];
#pragma unroll
    for (int m = 0; m < 4; ++m) {
#pragma unroll
      for (int r = 0; r < 4; ++r) {
        const int row = bm + wr * 64 + m * 16 + lg4 + r;
        if (row < M) {
          float v = acc[m][n][r] + bv;
          if (EPI == 1) v = fmaxf(v, 0.f);
          C[(size_t)row * N + col] = v;
        }
      }
    }
  }
}

// ---------------- build h_in = concat([ctx, x], axis=1) rows: r = b*129 + t --
__global__ __launch_bounds__(256) void build_hin(const float* __restrict__ x,
                                                 const float* __restrict__ ctx,
                                                 float* __restrict__ hin) {
  const int r = blockIdx.x;
  const int b = r / SEQ, t = r % SEQ;
  const float* src = (t == 0) ? (ctx + (size_t)b * IN_DIM)
                              : (x + ((size_t)b * S_ + (t - 1)) * IN_DIM);
  f32x4 v = *(const f32x4*)(src + threadIdx.x * 4);
  *(f32x4*)(hin + (size_t)r * IN_DIM + threadIdx.x * 4) = v;
}

// ---------------- attention over batch axis (32) at each (pos t, head) ------
__global__ __launch_bounds__(128) void attention_kern(const float* __restrict__ qkv,
                                                      float* __restrict__ o) {
  __shared__ alignas(16) float qs[32][132], ks[32][132], vs[32][132];
  __shared__ float ps[32][33];
  const int t = blockIdx.x, hd = blockIdx.y, tid = threadIdx.x;
  for (int i = tid; i < 32 * 32; i += 128) {   // 32 rows x 32 float4
    const int bb = i >> 5, d4 = (i & 31) << 2;
    const size_t base = (size_t)(bb * SEQ + t) * (3 * HD) + hd * DH + d4;
    *(f32x4*)&qs[bb][d4] = *(const f32x4*)(qkv + base);
    *(f32x4*)&ks[bb][d4] = *(const f32x4*)(qkv + base + HD);
    *(f32x4*)&vs[bb][d4] = *(const f32x4*)(qkv + base + 2 * HD);
  }
  __syncthreads();
  const float scale = 0.08838834764831845f;   // 1/sqrt(128)
  for (int idx = tid; idx < 1024; idx += 128) {
    const int i = idx >> 5, j = idx & 31;
    float s = 0.f;
#pragma unroll 8
    for (int d = 0; d < DH; ++d) s += qs[i][d] * ks[j][d];
    ps[i][j] = s * scale;
  }
  __syncthreads();
  if (tid < 32) {
    float mx = -1e30f;
#pragma unroll
    for (int j = 0; j < 32; ++j) mx = fmaxf(mx, ps[tid][j]);
    float sum = 0.f;
#pragma unroll
    for (int j = 0; j < 32; ++j) { float e = __expf(ps[tid][j] - mx); ps[tid][j] = e; sum += e; }
    const float inv = 1.f / sum;
#pragma unroll
    for (int j = 0; j < 32; ++j) ps[tid][j] *= inv;
  }
  __syncthreads();
  for (int idx = tid; idx < 32 * DH; idx += 128) {  // one row per iteration
    const int i = idx >> 7, d = idx & 127;
    float s = 0.f;
#pragma unroll
    for (int j = 0; j < 32; ++j) s += ps[i][j] * vs[j][d];
    o[(size_t)(i * SEQ + t) * HD + hd * DH + d] = s;
  }
}

// ---------------- y = LN(h + delta) * g + b  (row-wise over H=1024) ---------
__global__ __launch_bounds__(256) void add_ln(const float* __restrict__ hin,
                                              const float* __restrict__ delta,
                                              const float* __restrict__ g,
                                              const float* __restrict__ bb,
                                              float* __restrict__ hout) {
  const int r = blockIdx.x, tid = threadIdx.x;
  const f32x4 hv = *(const f32x4*)(hin + (size_t)r * HD + tid * 4);
  const f32x4 dv = *(const f32x4*)(delta + (size_t)r * HD + tid * 4);
  f32x4 s = hv + dv;
  float ls = s.x + s.y + s.z + s.w;
  float l2 = s.x * s.x + s.y * s.y + s.z * s.z + s.w * s.w;
#pragma unroll
  for (int off = 32; off > 0; off >>= 1) {
    ls += __shfl_down(ls, off);
    l2 += __shfl_down(l2, off);
  }
  __shared__ float red[8];
  const int wave = tid >> 6, lane = tid & 63;
  if (lane == 0) { red[wave * 2] = ls; red[wave * 2 + 1] = l2; }
  __syncthreads();
  if (tid == 0) {
    float a = 0.f, b2 = 0.f;
    for (int w = 0; w < 4; ++w) { a += red[w * 2]; b2 += red[w * 2 + 1]; }
    red[0] = a; red[1] = b2;
  }
  __syncthreads();
  const float mean = red[0] * (1.f / HD);
  const float var  = red[1] * (1.f / HD) - mean * mean;
  const float inv  = rsqrtf(var + 1e-5f);
  const f32x4 gv = *(const f32x4*)(g + tid * 4);
  const f32x4 bv = *(const f32x4*)(bb + tid * 4);
  f32x4 y;
  y.x = (s.x - mean) * inv * gv.x + bv.x;
  y.y = (s.y - mean) * inv * gv.y + bv.y;
  y.z = (s.z - mean) * inv * gv.z + bv.z;
  y.w = (s.w - mean) * inv * gv.w + bv.w;
  *(f32x4*)(hout + (size_t)r * HD + tid * 4) = y;
}

// ---------------- pred[b][s][c] = out[b*129 + s+1][c] ------------------------
__global__ __launch_bounds__(256) void write_pred(const float* __restrict__ outb,
                                                  float* __restrict__ pred) {
  const int bs = blockIdx.x;                 // 0..4095
  const int b = bs >> 7, s = bs & 127;
  pred[(size_t)bs * OUT_DIM + threadIdx.x] =
      outb[((size_t)b * SEQ + s + 1) * OUT_DIM + threadIdx.x];
}

// ---------------- gather cand, write cand part of cand_out, d = cand - pred --
__global__ __launch_bounds__(256) void gather_cand(const float* __restrict__ outb,
                                                   const int* __restrict__ indices,
                                                   const float* __restrict__ KB,
                                                   float* __restrict__ cand_out,
                                                   float* __restrict__ dbuf) {
  const int bs = blockIdx.x;                 // 0..4095
  const int b = bs >> 7, s = bs & 127;
  const int c = threadIdx.x;                 // 0..255
  const float p = outb[((size_t)b * SEQ + s + 1) * OUT_DIM + c];
  const int* idxp = indices + (size_t)bs * KC;
  for (int k = 0; k < KC; ++k) {
    int idx = idxp[k];
    if (idx < 0) idx = 0;
    const float cv = KB[(size_t)idx * OUT_DIM + c];
    const size_t row = (size_t)bs * KC + k;
    cand_out[row * 257 + 1 + c] = cv;
    dbuf[row * OUT_DIM + c] = cv - p;
  }
}

// ---------------- ds = t1(relu'd) . W2 + b2 -> cand_out[row*257] ------------
__global__ __launch_bounds__(256) void score_reduce(const float* __restrict__ t1,
                                                    const float* __restrict__ W2,
                                                    const float* __restrict__ b2,
                                                    float* __restrict__ cand_out) {
  const int wave = threadIdx.x >> 6, lane = threadIdx.x & 63;
  const size_t row = (size_t)blockIdx.x * 4 + wave;
  const float* tp = t1 + row * OUT_DIM;
  float sum = 0.f;
  for (int c = lane; c < OUT_DIM; c += 64) sum += tp[c] * W2[c];
#pragma unroll
  for (int off = 32; off > 0; off >>= 1) sum += __shfl_down(sum, off);
  if (lane == 0) cand_out[row * 257] = sum + b2[0];
}

extern "C" void kernel_launch(void* const* d_in, const int* in_sizes, int n_in,
                              void* d_out, int out_size, void* d_ws, size_t ws_size,
                              hipStream_t stream) {
  const float* x      = (const float*)d_in[0];
  const float* ctx    = (const float*)d_in[1];
  const int*   indices= (const int*)d_in[2];
  const float* KB     = (const float*)d_in[3];
  const float* W_in   = (const float*)d_in[4];
  const float* b_in   = (const float*)d_in[5];
  const float* Wqkv   = (const float*)d_in[6];
  const float* bqkv   = (const float*)d_in[7];
  const float* Wo     = (const float*)d_in[8];
  const float* bo     = (const float*)d_in[9];
  const float* ln1_g  = (const float*)d_in[10];
  const float* ln1_b  = (const float*)d_in[11];
  const float* W1     = (const float*)d_in[12];
  const float* b1     = (const float*)d_in[13];
  const float* W2     = (const float*)d_in[14];
  const float* b2     = (const float*)d_in[15];
  const float* ln2_g  = (const float*)d_in[16];
  const float* ln2_b  = (const float*)d_in[17];
  const float* W_out  = (const float*)d_in[18];
  const float* b_out  = (const float*)d_in[19];
  const float* ds_W1  = (const float*)d_in[20];
  const float* ds_b1  = (const float*)d_in[21];
  const float* ds_W2  = (const float*)d_in[22];
  const float* ds_b2  = (const float*)d_in[23];
  // d_in[24..27] = cs_* : dead code in reference (del cs)

  char* p = (char*)d_ws;
  auto alloc = [&](size_t bytes) {
    char* q = p;
    p += (bytes + 255) & ~(size_t)255;
    return q;
  };
  float* h    = (float*)alloc((size_t)MROWS * HD * 4);
  float* tmp1 = (float*)alloc((size_t)MROWS * 3 * HD * 4);  // qkv / ff1
  float* tmp2 = (float*)alloc((size_t)MROWS * HD * 4);      // hin / o
  float* tmp3 = (float*)alloc((size_t)MROWS * HD * 4);      // attn_out / ff2
  float* outb = (float*)alloc((size_t)MROWS * OUT_DIM * 4);
  float* dbuf = (float*)alloc((size_t)NCAND * OUT_DIM * 4);
  float* t1   = (float*)alloc((size_t)NCAND * OUT_DIM * 4);
  short* WinT  = (short*)alloc((size_t)HD * IN_DIM * 2);
  short* WqkvT = (short*)alloc((size_t)2 * 3 * HD * HD * 2);
  short* WoT   = (short*)alloc((size_t)2 * HD * HD * 2);
  short* W1T   = (short*)alloc((size_t)2 * DFF * HD * 2);
  short* W2T   = (short*)alloc((size_t)2 * HD * DFF * 2);
  short* WoutT = (short*)alloc((size_t)OUT_DIM * HD * 2);
  short* dsW1T = (short*)alloc((size_t)OUT_DIM * OUT_DIM * 2);

  // weight transposes (f32 -> bf16, N x K)
  transpose_bf16<<<dim3(32, 32), 256, 0, stream>>>(W_in, WinT, 1024, 1024);
  for (int l = 0; l < 2; ++l) {
    transpose_bf16<<<dim3(96, 32), 256, 0, stream>>>(
        Wqkv + (size_t)l * 1024 * 3072, WqkvT + (size_t)l * 3072 * 1024, 1024, 3072);
    transpose_bf16<<<dim3(32, 32), 256, 0, stream>>>(
        Wo + (size_t)l * 1024 * 1024, WoT + (size_t)l * 1024 * 1024, 1024, 1024);
    transpose_bf16<<<dim3(64, 32), 256, 0, stream>>>(
        W1 + (size_t)l * 1024 * 2048, W1T + (size_t)l * 2048 * 1024, 1024, 2048);
    transpose_bf16<<<dim3(32, 64), 256, 0, stream>>>(
        W2 + (size_t)l * 2048 * 1024, W2T + (size_t)l * 1024 * 2048, 2048, 1024);
  }
  transpose_bf16<<<dim3(8, 32), 256, 0, stream>>>(W_out, WoutT, 1024, 256);
  transpose_bf16<<<dim3(8, 8), 256, 0, stream>>>(ds_W1, dsW1T, 256, 256);

  // forward
  build_hin<<<MROWS, 256, 0, stream>>>(x, ctx, tmp2);
  gemm_bt<1><<<dim3(33, 8), 256, 0, stream>>>(tmp2, WinT, b_in, h, MROWS, 1024, 1024);

  for (int l = 0; l < 2; ++l) {
    gemm_bt<0><<<dim3(33, 24), 256, 0, stream>>>(
        h, WqkvT + (size_t)l * 3072 * 1024, bqkv + l * 3072, tmp1, MROWS, 3072, 1024);
    attention_kern<<<dim3(SEQ, NHEAD), 128, 0, stream>>>(tmp1, tmp2);
    gemm_bt<0><<<dim3(33, 8), 256, 0, stream>>>(
        tmp2, WoT + (size_t)l * 1024 * 1024, bo + l * 1024, tmp3, MROWS, 1024, 1024);
    add_ln<<<MROWS, 256, 0, stream>>>(h, tmp3, ln1_g + l * 1024, ln1_b + l * 1024, h);
    gemm_bt<1><<<dim3(33, 16), 256, 0, stream>>>(
        h, W1T + (size_t)l * 2048 * 1024, b1 + l * 2048, tmp1, MROWS, 2048, 1024);
    gemm_bt<0><<<dim3(33, 8), 256, 0, stream>>>(
        tmp1, W2T + (size_t)l * 1024 * 2048, b2 + l * 1024, tmp3, MROWS, 1024, 2048);
    add_ln<<<MROWS, 256, 0, stream>>>(h, tmp3, ln2_g + l * 1024, ln2_b + l * 1024, h);
  }

  gemm_bt<0><<<dim3(33, 2), 256, 0, stream>>>(h, WoutT, b_out, outb, MROWS, 256, 1024);

  float* pred = (float*)d_out;
  float* cand_out = (float*)d_out + (size_t)B_ * S_ * OUT_DIM;
  write_pred<<<4096, 256, 0, stream>>>(outb, pred);
  gather_cand<<<4096, 256, 0, stream>>>(outb, indices, KB, cand_out, dbuf);
  gemm_bt<1><<<dim3(320, 2), 256, 0, stream>>>(dbuf, dsW1T, ds_b1, t1, NCAND, 256, 256);
  score_reduce<<<NCAND / 4, 256, 0, stream>>>(t1, ds_W2, ds_b2, cand_out);
}

// Round 2
// 618.448 us; speedup vs baseline: 1.3993x; 1.3993x over previous
//
#include <hip/hip_runtime.h>
#include <hip/hip_bf16.h>

typedef __attribute__((ext_vector_type(4))) float f32x4;
typedef __attribute__((ext_vector_type(8))) short s16x8;
typedef __attribute__((ext_vector_type(4))) unsigned short u16x4;

#define B_      32
#define S_      128
#define SEQ     129
#define IN_DIM  1024
#define HD      1024
#define NHEAD   8
#define DH      128
#define OUT_DIM 256
#define KC      10
#define DFF     2048
#define MROWS   (B_*SEQ)     // 4128
#define MPAD    4224         // 33 * 128
#define NCAND   (B_*S_*KC)   // 40960

__device__ __forceinline__ short f2bf(float f) {
  unsigned u = __builtin_bit_cast(unsigned, f);
  u += 0x7FFFu + ((u >> 16) & 1u);   // RNE to bf16
  return (short)(u >> 16);
}
__device__ __forceinline__ float bf2f(short s) {
  return __builtin_bit_cast(float, ((unsigned)(unsigned short)s) << 16);
}
__device__ __forceinline__ void gload16(const short* g, short* l) {
  __builtin_amdgcn_global_load_lds(
      (const __attribute__((address_space(1))) unsigned*)g,
      (__attribute__((address_space(3))) unsigned*)l, 16, 0, 0);
}

// ---------------- transpose + convert: W[K][N] f32 -> Wt[N][K] bf16 ----------
__global__ __launch_bounds__(256) void transpose_bf16(const float* __restrict__ W,
                                                      short* __restrict__ Wt,
                                                      int K, int N) {
  __shared__ float tile[32][33];
  const int n0 = blockIdx.x << 5, k0 = blockIdx.y << 5;
  const int tx = threadIdx.x & 31, ty = threadIdx.x >> 5;  // 32 x 8
#pragma unroll
  for (int i = 0; i < 4; ++i)
    tile[ty + i * 8][tx] = W[(size_t)(k0 + ty + i * 8) * N + n0 + tx];
  __syncthreads();
#pragma unroll
  for (int i = 0; i < 4; ++i)
    Wt[(size_t)(n0 + ty + i * 8) * K + k0 + tx] = f2bf(tile[tx][ty + i * 8]);
}

// ---------------- GEMM: C[M][N] = A[M][K](bf16) * Bt[N][K](bf16) + bias ------
// EPI: 0 none, 1 relu.  OutT: float or short (bf16).
// A must be padded so rows [bm, bm+128) are readable. N % 128 == 0, K % 32 == 0.
template <int EPI, typename OutT>
__global__ __launch_bounds__(256) void gemm_bt(const short* __restrict__ A,
                                               const short* __restrict__ Bt,
                                               const float* __restrict__ bias,
                                               OutT* __restrict__ C,
                                               int M, int N, int K) {
  __shared__ alignas(16) short As[4096];   // 128 rows x 32 bf16 (64B rows)
  __shared__ alignas(16) short Bs[4096];
  const int tid = threadIdx.x;
  const int lane = tid & 63, wave = tid >> 6;
  const int wr = wave >> 1, wc = wave & 1;          // 2x2 waves, 64x64 each
  const int bm = blockIdx.x * 128, bn = blockIdx.y * 128;

  // staging (pre-swizzled global source; linear LDS dest via global_load_lds)
  // issue i in {0,1}: idx = i*256 + tid; row r = idx>>2; slot s = idx&3;
  // global slot g = s ^ ((r>>1)&3)
  const short* pa[2];
  const short* pb[2];
#pragma unroll
  for (int i = 0; i < 2; ++i) {
    const int idx = i * 256 + tid;
    const int r = idx >> 2, s = idx & 3, g = s ^ ((r >> 1) & 3);
    pa[i] = A + (size_t)(bm + r) * K + g * 8;
    pb[i] = Bt + (size_t)(bn + r) * K + g * 8;
  }
  short* lA0 = As + wave * 512;          // wave-uniform LDS bases
  short* lA1 = As + 2048 + wave * 512;
  short* lB0 = Bs + wave * 512;
  short* lB1 = Bs + 2048 + wave * 512;

  // fragment read offsets (swizzled): row rr, k-slot ks -> shorts rr*32 + ((ks^sx)<<3)
  const int lrow = lane & 15, ks = lane >> 4;
  const int sx = (lrow >> 1) & 3;
  const int koff = ((ks ^ sx) << 3);

  f32x4 acc[4][4] = {};

  for (int k0 = 0; k0 < K; k0 += 32) {
    gload16(pa[0] + k0, lA0);
    gload16(pa[1] + k0, lA1);
    gload16(pb[0] + k0, lB0);
    gload16(pb[1] + k0, lB1);
    __syncthreads();   // compiler emits vmcnt(0) drain before barrier

    s16x8 af[4], bfr[4];
#pragma unroll
    for (int m = 0; m < 4; ++m)
      af[m] = *(const s16x8*)&As[(wr * 64 + m * 16 + lrow) * 32 + koff];
#pragma unroll
    for (int n = 0; n < 4; ++n)
      bfr[n] = *(const s16x8*)&Bs[(wc * 64 + n * 16 + lrow) * 32 + koff];
#pragma unroll
    for (int m = 0; m < 4; ++m)
#pragma unroll
      for (int n = 0; n < 4; ++n)
        asm("v_mfma_f32_16x16x32_bf16 %0, %1, %2, %0"
            : "+v"(acc[m][n]) : "v"(af[m]), "v"(bfr[n]));
    __syncthreads();
  }

  const int lg4 = ks << 2;
#pragma unroll
  for (int n = 0; n < 4; ++n) {
    const int col = bn + wc * 64 + n * 16 + lrow;
    const float bv = bias[col];
#pragma unroll
    for (int m = 0; m < 4; ++m) {
#pragma unroll
      for (int r = 0; r < 4; ++r) {
        const int row = bm + wr * 64 + m * 16 + lg4 + r;
        if (row < M) {
          float v = acc[m][n][r] + bv;
          if (EPI == 1) v = fmaxf(v, 0.f);
          if constexpr (__is_same(OutT, float)) {
            C[(size_t)row * N + col] = v;
          } else {
            C[(size_t)row * N + col] = f2bf(v);
          }
        }
      }
    }
  }
}

// ---------------- build h_in = concat([ctx, x], axis=1) -> bf16 --------------
__global__ __launch_bounds__(256) void build_hin(const float* __restrict__ x,
                                                 const float* __restrict__ ctx,
                                                 short* __restrict__ hin) {
  const int r = blockIdx.x;
  const int b = r / SEQ, t = r % SEQ;
  const float* src = (t == 0) ? (ctx + (size_t)b * IN_DIM)
                              : (x + ((size_t)b * S_ + (t - 1)) * IN_DIM);
  f32x4 v = *(const f32x4*)(src + threadIdx.x * 4);
  u16x4 o;
  o.x = (unsigned short)f2bf(v.x); o.y = (unsigned short)f2bf(v.y);
  o.z = (unsigned short)f2bf(v.z); o.w = (unsigned short)f2bf(v.w);
  *(u16x4*)(hin + (size_t)r * IN_DIM + threadIdx.x * 4) = o;
}

// ---------------- attention over batch axis (32) at each (pos t, head) ------
__global__ __launch_bounds__(128) void attention_kern(const short* __restrict__ qkv,
                                                      short* __restrict__ o) {
  __shared__ alignas(16) float qs[32][132], ksm[32][132], vs[32][132];
  __shared__ float ps[32][33];
  const int t = blockIdx.x, hd = blockIdx.y, tid = threadIdx.x;
  for (int i = tid; i < 32 * 16; i += 128) {   // 32 rows x 16 chunks of 8 bf16
    const int bb = i >> 4, d8 = (i & 15) << 3;
    const size_t base = (size_t)(bb * SEQ + t) * (3 * HD) + hd * DH + d8;
    s16x8 q8 = *(const s16x8*)(qkv + base);
    s16x8 k8 = *(const s16x8*)(qkv + base + HD);
    s16x8 v8 = *(const s16x8*)(qkv + base + 2 * HD);
#pragma unroll
    for (int j = 0; j < 8; ++j) {
      qs[bb][d8 + j] = bf2f(q8[j]);
      ksm[bb][d8 + j] = bf2f(k8[j]);
      vs[bb][d8 + j] = bf2f(v8[j]);
    }
  }
  __syncthreads();
  const float scale = 0.08838834764831845f;   // 1/sqrt(128)
  for (int idx = tid; idx < 1024; idx += 128) {
    const int i = idx >> 5, j = idx & 31;
    float s = 0.f;
#pragma unroll 8
    for (int d = 0; d < DH; ++d) s += qs[i][d] * ksm[j][d];
    ps[i][j] = s * scale;
  }
  __syncthreads();
  if (tid < 32) {
    float mx = -1e30f;
#pragma unroll
    for (int j = 0; j < 32; ++j) mx = fmaxf(mx, ps[tid][j]);
    float sum = 0.f;
#pragma unroll
    for (int j = 0; j < 32; ++j) { float e = __expf(ps[tid][j] - mx); ps[tid][j] = e; sum += e; }
    const float inv = 1.f / sum;
#pragma unroll
    for (int j = 0; j < 32; ++j) ps[tid][j] *= inv;
  }
  __syncthreads();
  for (int idx = tid; idx < 32 * DH; idx += 128) {
    const int i = idx >> 7, d = idx & 127;
    float s = 0.f;
#pragma unroll
    for (int j = 0; j < 32; ++j) s += ps[i][j] * vs[j][d];
    o[(size_t)(i * SEQ + t) * HD + hd * DH + d] = f2bf(s);
  }
}

// ---------------- y = LN(h + delta) * g + b  (bf16 in / bf16 out) -----------
__global__ __launch_bounds__(256) void add_ln(const short* __restrict__ hin,
                                              const short* __restrict__ delta,
                                              const float* __restrict__ g,
                                              const float* __restrict__ bb,
                                              short* __restrict__ hout) {
  const int r = blockIdx.x, tid = threadIdx.x;
  const u16x4 hv = *(const u16x4*)(hin + (size_t)r * HD + tid * 4);
  const u16x4 dv = *(const u16x4*)(delta + (size_t)r * HD + tid * 4);
  float s0 = bf2f((short)hv.x) + bf2f((short)dv.x);
  float s1 = bf2f((short)hv.y) + bf2f((short)dv.y);
  float s2 = bf2f((short)hv.z) + bf2f((short)dv.z);
  float s3 = bf2f((short)hv.w) + bf2f((short)dv.w);
  float ls = s0 + s1 + s2 + s3;
  float l2 = s0 * s0 + s1 * s1 + s2 * s2 + s3 * s3;
#pragma unroll
  for (int off = 32; off > 0; off >>= 1) {
    ls += __shfl_down(ls, off);
    l2 += __shfl_down(l2, off);
  }
  __shared__ float red[8];
  const int wave = tid >> 6, lane = tid & 63;
  if (lane == 0) { red[wave * 2] = ls; red[wave * 2 + 1] = l2; }
  __syncthreads();
  if (tid == 0) {
    float a = 0.f, b2 = 0.f;
    for (int w = 0; w < 4; ++w) { a += red[w * 2]; b2 += red[w * 2 + 1]; }
    red[0] = a; red[1] = b2;
  }
  __syncthreads();
  const float mean = red[0] * (1.f / HD);
  const float var  = red[1] * (1.f / HD) - mean * mean;
  const float inv  = rsqrtf(var + 1e-5f);
  const f32x4 gv = *(const f32x4*)(g + tid * 4);
  const f32x4 bv = *(const f32x4*)(bb + tid * 4);
  u16x4 y;
  y.x = (unsigned short)f2bf((s0 - mean) * inv * gv.x + bv.x);
  y.y = (unsigned short)f2bf((s1 - mean) * inv * gv.y + bv.y);
  y.z = (unsigned short)f2bf((s2 - mean) * inv * gv.z + bv.z);
  y.w = (unsigned short)f2bf((s3 - mean) * inv * gv.w + bv.w);
  *(u16x4*)(hout + (size_t)r * HD + tid * 4) = y;
}

// ---------------- pred[b][s][c] = out[b*129 + s+1][c] (fp32) -----------------
__global__ __launch_bounds__(256) void write_pred(const float* __restrict__ outb,
                                                  float* __restrict__ pred) {
  const int bs = blockIdx.x;
  const int b = bs >> 7, s = bs & 127;
  pred[(size_t)bs * OUT_DIM + threadIdx.x] =
      outb[((size_t)b * SEQ + s + 1) * OUT_DIM + threadIdx.x];
}

// ---------------- gather cand, write cand_out[..,1:], dbuf = bf16(cand-pred) -
__global__ __launch_bounds__(256) void gather_cand(const float* __restrict__ outb,
                                                   const int* __restrict__ indices,
                                                   const float* __restrict__ KB,
                                                   float* __restrict__ cand_out,
                                                   short* __restrict__ dbuf) {
  const int bs = blockIdx.x;
  const int b = bs >> 7, s = bs & 127;
  const int c = threadIdx.x;
  const float p = outb[((size_t)b * SEQ + s + 1) * OUT_DIM + c];
  const int* idxp = indices + (size_t)bs * KC;
  for (int k = 0; k < KC; ++k) {
    int idx = idxp[k];
    if (idx < 0) idx = 0;
    const float cv = KB[(size_t)idx * OUT_DIM + c];
    const size_t row = (size_t)bs * KC + k;
    cand_out[row * 257 + 1 + c] = cv;
    dbuf[row * OUT_DIM + c] = f2bf(cv - p);
  }
}

// ---------------- ds = t1(bf16, relu'd) . W2 + b2 -> cand_out[row*257] ------
__global__ __launch_bounds__(256) void score_reduce(const short* __restrict__ t1,
                                                    const float* __restrict__ W2,
                                                    const float* __restrict__ b2,
                                                    float* __restrict__ cand_out) {
  const int wave = threadIdx.x >> 6, lane = threadIdx.x & 63;
  const size_t row = (size_t)blockIdx.x * 4 + wave;
  const short* tp = t1 + row * OUT_DIM;
  float sum = 0.f;
  for (int c = lane; c < OUT_DIM; c += 64) sum += bf2f(tp[c]) * W2[c];
#pragma unroll
  for (int off = 32; off > 0; off >>= 1) sum += __shfl_down(sum, off);
  if (lane == 0) cand_out[row * 257] = sum + b2[0];
}

extern "C" void kernel_launch(void* const* d_in, const int* in_sizes, int n_in,
                              void* d_out, int out_size, void* d_ws, size_t ws_size,
                              hipStream_t stream) {
  const float* x      = (const float*)d_in[0];
  const float* ctx    = (const float*)d_in[1];
  const int*   indices= (const int*)d_in[2];
  const float* KB     = (const float*)d_in[3];
  const float* W_in   = (const float*)d_in[4];
  const float* b_in   = (const float*)d_in[5];
  const float* Wqkv   = (const float*)d_in[6];
  const float* bqkv   = (const float*)d_in[7];
  const float* Wo     = (const float*)d_in[8];
  const float* bo     = (const float*)d_in[9];
  const float* ln1_g  = (const float*)d_in[10];
  const float* ln1_b  = (const float*)d_in[11];
  const float* W1     = (const float*)d_in[12];
  const float* b1     = (const float*)d_in[13];
  const float* W2     = (const float*)d_in[14];
  const float* b2     = (const float*)d_in[15];
  const float* ln2_g  = (const float*)d_in[16];
  const float* ln2_b  = (const float*)d_in[17];
  const float* W_out  = (const float*)d_in[18];
  const float* b_out  = (const float*)d_in[19];
  const float* ds_W1  = (const float*)d_in[20];
  const float* ds_b1  = (const float*)d_in[21];
  const float* ds_W2  = (const float*)d_in[22];
  const float* ds_b2  = (const float*)d_in[23];
  // d_in[24..27] = cs_* : dead code in reference (del cs)

  char* p = (char*)d_ws;
  auto alloc = [&](size_t bytes) {
    char* q = p;
    p += (bytes + 255) & ~(size_t)255;
    return q;
  };
  short* h    = (short*)alloc((size_t)MPAD * HD * 2);
  short* tmp1 = (short*)alloc((size_t)MPAD * 3 * HD * 2);  // qkv / ff1
  short* tmp2 = (short*)alloc((size_t)MPAD * HD * 2);      // hin / attn-o
  short* tmp3 = (short*)alloc((size_t)MPAD * HD * 2);      // Wo out / ff2
  float* outb = (float*)alloc((size_t)MROWS * OUT_DIM * 4);
  short* dbuf = (short*)alloc((size_t)NCAND * OUT_DIM * 2);
  short* t1   = (short*)alloc((size_t)NCAND * OUT_DIM * 2);
  short* WinT  = (short*)alloc((size_t)HD * IN_DIM * 2);
  short* WqkvT = (short*)alloc((size_t)2 * 3 * HD * HD * 2);
  short* WoT   = (short*)alloc((size_t)2 * HD * HD * 2);
  short* W1T   = (short*)alloc((size_t)2 * DFF * HD * 2);
  short* W2T   = (short*)alloc((size_t)2 * HD * DFF * 2);
  short* WoutT = (short*)alloc((size_t)OUT_DIM * HD * 2);
  short* dsW1T = (short*)alloc((size_t)OUT_DIM * OUT_DIM * 2);

  // weight transposes (f32 -> bf16, N x K)
  transpose_bf16<<<dim3(32, 32), 256, 0, stream>>>(W_in, WinT, 1024, 1024);
  for (int l = 0; l < 2; ++l) {
    transpose_bf16<<<dim3(96, 32), 256, 0, stream>>>(
        Wqkv + (size_t)l * 1024 * 3072, WqkvT + (size_t)l * 3072 * 1024, 1024, 3072);
    transpose_bf16<<<dim3(32, 32), 256, 0, stream>>>(
        Wo + (size_t)l * 1024 * 1024, WoT + (size_t)l * 1024 * 1024, 1024, 1024);
    transpose_bf16<<<dim3(64, 32), 256, 0, stream>>>(
        W1 + (size_t)l * 1024 * 2048, W1T + (size_t)l * 2048 * 1024, 1024, 2048);
    transpose_bf16<<<dim3(32, 64), 256, 0, stream>>>(
        W2 + (size_t)l * 2048 * 1024, W2T + (size_t)l * 1024 * 2048, 2048, 1024);
  }
  transpose_bf16<<<dim3(8, 32), 256, 0, stream>>>(W_out, WoutT, 1024, 256);
  transpose_bf16<<<dim3(8, 8), 256, 0, stream>>>(ds_W1, dsW1T, 256, 256);

  // forward
  build_hin<<<MROWS, 256, 0, stream>>>(x, ctx, tmp2);
  gemm_bt<1, short><<<dim3(33, 8), 256, 0, stream>>>(tmp2, WinT, b_in, h, MROWS, 1024, 1024);

  for (int l = 0; l < 2; ++l) {
    gemm_bt<0, short><<<dim3(33, 24), 256, 0, stream>>>(
        h, WqkvT + (size_t)l * 3072 * 1024, bqkv + l * 3072, tmp1, MROWS, 3072, 1024);
    attention_kern<<<dim3(SEQ, NHEAD), 128, 0, stream>>>(tmp1, tmp2);
    gemm_bt<0, short><<<dim3(33, 8), 256, 0, stream>>>(
        tmp2, WoT + (size_t)l * 1024 * 1024, bo + l * 1024, tmp3, MROWS, 1024, 1024);
    add_ln<<<MROWS, 256, 0, stream>>>(h, tmp3, ln1_g + l * 1024, ln1_b + l * 1024, h);
    gemm_bt<1, short><<<dim3(33, 16), 256, 0, stream>>>(
        h, W1T + (size_t)l * 2048 * 1024, b1 + l * 2048, tmp1, MROWS, 2048, 1024);
    gemm_bt<0, short><<<dim3(33, 8), 256, 0, stream>>>(
        tmp1, W2T + (size_t)l * 1024 * 2048, b2 + l * 1024, tmp3, MROWS, 1024, 2048);
    add_ln<<<MROWS, 256, 0, stream>>>(h, tmp3, ln2_g + l * 1024, ln2_b + l * 1024, h);
  }

  gemm_bt<0, float><<<dim3(33, 2), 256, 0, stream>>>(h, WoutT, b_out, outb, MROWS, 256, 1024);

  float* pred = (float*)d_out;
  float* cand_out = (float*)d_out + (size_t)B_ * S_ * OUT_DIM;
  write_pred<<<4096, 256, 0, stream>>>(outb, pred);
  gather_cand<<<4096, 256, 0, stream>>>(outb, indices, KB, cand_out, dbuf);
  gemm_bt<1, short><<<dim3(320, 2), 256, 0, stream>>>(dbuf, dsW1T, ds_b1, t1, NCAND, 256, 256);
  score_reduce<<<NCAND / 4, 256, 0, stream>>>(t1, ds_W2, ds_b2, cand_out);
}

// Round 3
// 582.496 us; speedup vs baseline: 1.4856x; 1.0617x over previous
//
#include <hip/hip_runtime.h>
#include <hip/hip_bf16.h>

typedef __attribute__((ext_vector_type(4))) float f32x4;
typedef __attribute__((ext_vector_type(8))) short s16x8;
typedef __attribute__((ext_vector_type(4))) unsigned short u16x4;

#define B_      32
#define S_      128
#define SEQ     129
#define IN_DIM  1024
#define HD      1024
#define NHEAD   8
#define DH      128
#define OUT_DIM 256
#define KC      10
#define DFF     2048
#define MROWS   (B_*SEQ)     // 4128
#define MPAD    4224         // 33 * 128
#define NCAND   (B_*S_*KC)   // 40960 = 320*128

__device__ __forceinline__ short f2bf(float f) {
  unsigned u = __builtin_bit_cast(unsigned, f);
  u += 0x7FFFu + ((u >> 16) & 1u);   // RNE to bf16
  return (short)(u >> 16);
}
__device__ __forceinline__ float bf2f(short s) {
  return __builtin_bit_cast(float, ((unsigned)(unsigned short)s) << 16);
}
__device__ __forceinline__ void gload16(const short* g, short* l) {
  __builtin_amdgcn_global_load_lds(
      (const __attribute__((address_space(1))) unsigned*)g,
      (__attribute__((address_space(3))) unsigned*)l, 16, 0, 0);
}

// ---------------- ALL weight transposes fused: W[K][N] f32 -> Wt[N][K] bf16 --
__global__ __launch_bounds__(256) void transpose_all(
    const float* __restrict__ W_in,  const float* __restrict__ Wqkv,
    const float* __restrict__ Wo,    const float* __restrict__ W1,
    const float* __restrict__ W2,    const float* __restrict__ W_out,
    const float* __restrict__ dsW1,
    short* __restrict__ WinT,  short* __restrict__ WqkvT,
    short* __restrict__ WoT,   short* __restrict__ W1T,
    short* __restrict__ W2T,   short* __restrict__ WoutT,
    short* __restrict__ dsW1T) {
  const int b = blockIdx.x;
  const float* src; short* dst; int K, N, local;
  if (b < 1024)       { src = W_in;  dst = WinT;  K = 1024; N = 1024; local = b; }
  else if (b < 7168)  { int l = (b - 1024) / 3072; local = (b - 1024) % 3072;
                        src = Wqkv + (size_t)l * 1024 * 3072;
                        dst = WqkvT + (size_t)l * 3072 * 1024; K = 1024; N = 3072; }
  else if (b < 9216)  { int l = (b - 7168) / 1024; local = (b - 7168) % 1024;
                        src = Wo + (size_t)l * 1024 * 1024;
                        dst = WoT + (size_t)l * 1024 * 1024; K = 1024; N = 1024; }
  else if (b < 13312) { int l = (b - 9216) / 2048; local = (b - 9216) % 2048;
                        src = W1 + (size_t)l * 1024 * 2048;
                        dst = W1T + (size_t)l * 2048 * 1024; K = 1024; N = 2048; }
  else if (b < 17408) { int l = (b - 13312) / 2048; local = (b - 13312) % 2048;
                        src = W2 + (size_t)l * 2048 * 1024;
                        dst = W2T + (size_t)l * 1024 * 2048; K = 2048; N = 1024; }
  else if (b < 17664) { local = b - 17408; src = W_out; dst = WoutT; K = 1024; N = 256; }
  else                { local = b - 17664; src = dsW1;  dst = dsW1T; K = 256;  N = 256; }
  const int tilesX = N >> 5;
  const int n0 = (local % tilesX) << 5, k0 = (local / tilesX) << 5;

  __shared__ float tile[32][33];
  const int tx = threadIdx.x & 31, ty = threadIdx.x >> 5;  // 32 x 8
#pragma unroll
  for (int i = 0; i < 4; ++i)
    tile[ty + i * 8][tx] = src[(size_t)(k0 + ty + i * 8) * N + n0 + tx];
  __syncthreads();
#pragma unroll
  for (int i = 0; i < 4; ++i)
    dst[(size_t)(n0 + ty + i * 8) * K + k0 + tx] = f2bf(tile[tx][ty + i * 8]);
}

// ---------------- GEMM: C[M][N] = A[M][K](bf16) * Bt[N][K](bf16) + bias ------
// 2-phase double-buffered (T3-lite): prefetch next K-tile via global_load_lds
// BEFORE computing current; single vmcnt(0)+barrier per K-step.
// A rows [bm, bm+128) must be readable (M padded). N%128==0, K%64==0.
template <int EPI, typename OutT>
__global__ __launch_bounds__(256) void gemm_bt(const short* __restrict__ A,
                                               const short* __restrict__ Bt,
                                               const float* __restrict__ bias,
                                               OutT* __restrict__ C,
                                               int M, int N, int K) {
  __shared__ alignas(16) short As0[4096], As1[4096];  // 128 rows x 32 bf16
  __shared__ alignas(16) short Bs0[4096], Bs1[4096];
  const int tid = threadIdx.x;
  const int lane = tid & 63, wave = tid >> 6;
  const int wr = wave >> 1, wc = wave & 1;          // 2x2 waves, 64x64 each
  const int bm = blockIdx.x * 128, bn = blockIdx.y * 128;

  // staging: pre-swizzled global source, linear LDS dest (global_load_lds).
  // slot idx = i*256 + tid; row r = idx>>2; lds 16B-slot s = idx&3;
  // global 16B-slot g = s ^ ((r>>1)&3)
  const short* pa[2];
  const short* pb[2];
#pragma unroll
  for (int i = 0; i < 2; ++i) {
    const int idx = i * 256 + tid;
    const int r = idx >> 2, s = idx & 3, g = s ^ ((r >> 1) & 3);
    pa[i] = A + (size_t)(bm + r) * K + g * 8;
    pb[i] = Bt + (size_t)(bn + r) * K + g * 8;
  }

  auto stage = [&](short* aBuf, short* bBuf, int kofs) {
    gload16(pa[0] + kofs, aBuf + wave * 512);
    gload16(pa[1] + kofs, aBuf + 2048 + wave * 512);
    gload16(pb[0] + kofs, bBuf + wave * 512);
    gload16(pb[1] + kofs, bBuf + 2048 + wave * 512);
  };

  // fragment reads (swizzled): row rr, k-slot ks -> shorts rr*32 + ((ks^sx)<<3)
  const int lrow = lane & 15, ks = lane >> 4;
  const int sx = (lrow >> 1) & 3;
  const int koff = ((ks ^ sx) << 3);

  f32x4 acc[4][4] = {};

  auto compute = [&](const short* as, const short* bs) {
    s16x8 af[4], bfr[4];
#pragma unroll
    for (int m = 0; m < 4; ++m)
      af[m] = *(const s16x8*)&as[(wr * 64 + m * 16 + lrow) * 32 + koff];
#pragma unroll
    for (int n = 0; n < 4; ++n)
      bfr[n] = *(const s16x8*)&bs[(wc * 64 + n * 16 + lrow) * 32 + koff];
#pragma unroll
    for (int m = 0; m < 4; ++m)
#pragma unroll
      for (int n = 0; n < 4; ++n)
        asm("v_mfma_f32_16x16x32_bf16 %0, %1, %2, %0"
            : "+v"(acc[m][n]) : "v"(af[m]), "v"(bfr[n]));
  };

  const int NT = K >> 5;                 // even for all call sites
  stage(As0, Bs0, 0);
  __syncthreads();                       // vmcnt(0) drain + barrier
  for (int t = 0; t < NT; t += 2) {
    stage(As1, Bs1, (t + 1) << 5);       // prefetch overlaps compute below
    compute(As0, Bs0);
    __syncthreads();
    if (t + 2 < NT) stage(As0, Bs0, (t + 2) << 5);
    compute(As1, Bs1);
    __syncthreads();
  }

  const int lg4 = ks << 2;
#pragma unroll
  for (int n = 0; n < 4; ++n) {
    const int col = bn + wc * 64 + n * 16 + lrow;
    const float bv = bias[col];
#pragma unroll
    for (int m = 0; m < 4; ++m) {
#pragma unroll
      for (int r = 0; r < 4; ++r) {
        const int row = bm + wr * 64 + m * 16 + lg4 + r;
        if (row < M) {
          float v = acc[m][n][r] + bv;
          if (EPI == 1) v = fmaxf(v, 0.f);
          if constexpr (__is_same(OutT, float)) {
            C[(size_t)row * N + col] = v;
          } else {
            C[(size_t)row * N + col] = f2bf(v);
          }
        }
      }
    }
  }
}

// ---------------- build h_in = concat([ctx, x], axis=1) -> bf16 --------------
__global__ __launch_bounds__(256) void build_hin(const float* __restrict__ x,
                                                 const float* __restrict__ ctx,
                                                 short* __restrict__ hin) {
  const int r = blockIdx.x;
  const int b = r / SEQ, t = r % SEQ;
  const float* src = (t == 0) ? (ctx + (size_t)b * IN_DIM)
                              : (x + ((size_t)b * S_ + (t - 1)) * IN_DIM);
  f32x4 v = *(const f32x4*)(src + threadIdx.x * 4);
  u16x4 o;
  o.x = (unsigned short)f2bf(v.x); o.y = (unsigned short)f2bf(v.y);
  o.z = (unsigned short)f2bf(v.z); o.w = (unsigned short)f2bf(v.w);
  *(u16x4*)(hin + (size_t)r * IN_DIM + threadIdx.x * 4) = o;
}

// ---------------- attention over batch axis (32) at each (pos t, head) ------
__global__ __launch_bounds__(128) void attention_kern(const short* __restrict__ qkv,
                                                      short* __restrict__ o) {
  __shared__ alignas(16) float qs[32][132], ksm[32][132], vs[32][132];
  __shared__ float ps[32][33];
  const int t = blockIdx.x, hd = blockIdx.y, tid = threadIdx.x;
  for (int i = tid; i < 32 * 16; i += 128) {   // 32 rows x 16 chunks of 8 bf16
    const int bb = i >> 4, d8 = (i & 15) << 3;
    const size_t base = (size_t)(bb * SEQ + t) * (3 * HD) + hd * DH + d8;
    s16x8 q8 = *(const s16x8*)(qkv + base);
    s16x8 k8 = *(const s16x8*)(qkv + base + HD);
    s16x8 v8 = *(const s16x8*)(qkv + base + 2 * HD);
#pragma unroll
    for (int j = 0; j < 8; ++j) {
      qs[bb][d8 + j] = bf2f(q8[j]);
      ksm[bb][d8 + j] = bf2f(k8[j]);
      vs[bb][d8 + j] = bf2f(v8[j]);
    }
  }
  __syncthreads();
  const float scale = 0.08838834764831845f;   // 1/sqrt(128)
  for (int idx = tid; idx < 1024; idx += 128) {
    const int i = idx >> 5, j = idx & 31;
    float s = 0.f;
#pragma unroll 8
    for (int d = 0; d < DH; ++d) s += qs[i][d] * ksm[j][d];
    ps[i][j] = s * scale;
  }
  __syncthreads();
  if (tid < 32) {
    float mx = -1e30f;
#pragma unroll
    for (int j = 0; j < 32; ++j) mx = fmaxf(mx, ps[tid][j]);
    float sum = 0.f;
#pragma unroll
    for (int j = 0; j < 32; ++j) { float e = __expf(ps[tid][j] - mx); ps[tid][j] = e; sum += e; }
    const float inv = 1.f / sum;
#pragma unroll
    for (int j = 0; j < 32; ++j) ps[tid][j] *= inv;
  }
  __syncthreads();
  for (int idx = tid; idx < 32 * DH; idx += 128) {
    const int i = idx >> 7, d = idx & 127;
    float s = 0.f;
#pragma unroll
    for (int j = 0; j < 32; ++j) s += ps[i][j] * vs[j][d];
    o[(size_t)(i * SEQ + t) * HD + hd * DH + d] = f2bf(s);
  }
}

// ---------------- y = LN(h + delta) * g + b  (bf16 in / bf16 out) -----------
__global__ __launch_bounds__(256) void add_ln(const short* __restrict__ hin,
                                              const short* __restrict__ delta,
                                              const float* __restrict__ g,
                                              const float* __restrict__ bb,
                                              short* __restrict__ hout) {
  const int r = blockIdx.x, tid = threadIdx.x;
  const u16x4 hv = *(const u16x4*)(hin + (size_t)r * HD + tid * 4);
  const u16x4 dv = *(const u16x4*)(delta + (size_t)r * HD + tid * 4);
  float s0 = bf2f((short)hv.x) + bf2f((short)dv.x);
  float s1 = bf2f((short)hv.y) + bf2f((short)dv.y);
  float s2 = bf2f((short)hv.z) + bf2f((short)dv.z);
  float s3 = bf2f((short)hv.w) + bf2f((short)dv.w);
  float ls = s0 + s1 + s2 + s3;
  float l2 = s0 * s0 + s1 * s1 + s2 * s2 + s3 * s3;
#pragma unroll
  for (int off = 32; off > 0; off >>= 1) {
    ls += __shfl_down(ls, off);
    l2 += __shfl_down(l2, off);
  }
  __shared__ float red[8];
  const int wave = tid >> 6, lane = tid & 63;
  if (lane == 0) { red[wave * 2] = ls; red[wave * 2 + 1] = l2; }
  __syncthreads();
  if (tid == 0) {
    float a = 0.f, b2 = 0.f;
    for (int w = 0; w < 4; ++w) { a += red[w * 2]; b2 += red[w * 2 + 1]; }
    red[0] = a; red[1] = b2;
  }
  __syncthreads();
  const float mean = red[0] * (1.f / HD);
  const float var  = red[1] * (1.f / HD) - mean * mean;
  const float inv  = rsqrtf(var + 1e-5f);
  const f32x4 gv = *(const f32x4*)(g + tid * 4);
  const f32x4 bv = *(const f32x4*)(bb + tid * 4);
  u16x4 y;
  y.x = (unsigned short)f2bf((s0 - mean) * inv * gv.x + bv.x);
  y.y = (unsigned short)f2bf((s1 - mean) * inv * gv.y + bv.y);
  y.z = (unsigned short)f2bf((s2 - mean) * inv * gv.z + bv.z);
  y.w = (unsigned short)f2bf((s3 - mean) * inv * gv.w + bv.w);
  *(u16x4*)(hout + (size_t)r * HD + tid * 4) = y;
}

// ---- pred write + gather cand + cand_out[..,1:] + dbuf = bf16(cand-pred) ----
__global__ __launch_bounds__(256) void gather_cand(const float* __restrict__ outb,
                                                   const int* __restrict__ indices,
                                                   const float* __restrict__ KB,
                                                   float* __restrict__ pred,
                                                   float* __restrict__ cand_out,
                                                   short* __restrict__ dbuf) {
  const int bs = blockIdx.x;
  const int b = bs >> 7, s = bs & 127;
  const int c = threadIdx.x;
  const float p = outb[((size_t)b * SEQ + s + 1) * OUT_DIM + c];
  pred[(size_t)bs * OUT_DIM + c] = p;
  const int* idxp = indices + (size_t)bs * KC;
  for (int k = 0; k < KC; ++k) {
    int idx = idxp[k];
    if (idx < 0) idx = 0;
    const float cv = KB[(size_t)idx * OUT_DIM + c];
    const size_t row = (size_t)bs * KC + k;
    cand_out[row * 257 + 1 + c] = cv;
    dbuf[row * OUT_DIM + c] = f2bf(cv - p);
  }
}

// ---------------- ds = t1(bf16, relu'd) . W2 + b2 -> cand_out[row*257] ------
__global__ __launch_bounds__(256) void score_reduce(const short* __restrict__ t1,
                                                    const float* __restrict__ W2,
                                                    const float* __restrict__ b2,
                                                    float* __restrict__ cand_out) {
  const int wave = threadIdx.x >> 6, lane = threadIdx.x & 63;
  const size_t row = (size_t)blockIdx.x * 4 + wave;
  const short* tp = t1 + row * OUT_DIM;
  float sum = 0.f;
  for (int c = lane; c < OUT_DIM; c += 64) sum += bf2f(tp[c]) * W2[c];
#pragma unroll
  for (int off = 32; off > 0; off >>= 1) sum += __shfl_down(sum, off);
  if (lane == 0) cand_out[row * 257] = sum + b2[0];
}

extern "C" void kernel_launch(void* const* d_in, const int* in_sizes, int n_in,
                              void* d_out, int out_size, void* d_ws, size_t ws_size,
                              hipStream_t stream) {
  const float* x      = (const float*)d_in[0];
  const float* ctx    = (const float*)d_in[1];
  const int*   indices= (const int*)d_in[2];
  const float* KB     = (const float*)d_in[3];
  const float* W_in   = (const float*)d_in[4];
  const float* b_in   = (const float*)d_in[5];
  const float* Wqkv   = (const float*)d_in[6];
  const float* bqkv   = (const float*)d_in[7];
  const float* Wo     = (const float*)d_in[8];
  const float* bo     = (const float*)d_in[9];
  const float* ln1_g  = (const float*)d_in[10];
  const float* ln1_b  = (const float*)d_in[11];
  const float* W1     = (const float*)d_in[12];
  const float* b1     = (const float*)d_in[13];
  const float* W2     = (const float*)d_in[14];
  const float* b2     = (const float*)d_in[15];
  const float* ln2_g  = (const float*)d_in[16];
  const float* ln2_b  = (const float*)d_in[17];
  const float* W_out  = (const float*)d_in[18];
  const float* b_out  = (const float*)d_in[19];
  const float* ds_W1  = (const float*)d_in[20];
  const float* ds_b1  = (const float*)d_in[21];
  const float* ds_W2  = (const float*)d_in[22];
  const float* ds_b2  = (const float*)d_in[23];
  // d_in[24..27] = cs_* : dead code in reference (del cs)

  char* p = (char*)d_ws;
  auto alloc = [&](size_t bytes) {
    char* q = p;
    p += (bytes + 255) & ~(size_t)255;
    return q;
  };
  short* h    = (short*)alloc((size_t)MPAD * HD * 2);
  short* tmp1 = (short*)alloc((size_t)MPAD * 3 * HD * 2);  // qkv / ff1
  short* tmp2 = (short*)alloc((size_t)MPAD * HD * 2);      // hin / attn-o
  short* tmp3 = (short*)alloc((size_t)MPAD * HD * 2);      // Wo out / ff2
  float* outb = (float*)alloc((size_t)MROWS * OUT_DIM * 4);
  short* dbuf = (short*)alloc((size_t)NCAND * OUT_DIM * 2);
  short* t1   = (short*)alloc((size_t)NCAND * OUT_DIM * 2);
  short* WinT  = (short*)alloc((size_t)HD * IN_DIM * 2);
  short* WqkvT = (short*)alloc((size_t)2 * 3 * HD * HD * 2);
  short* WoT   = (short*)alloc((size_t)2 * HD * HD * 2);
  short* W1T   = (short*)alloc((size_t)2 * DFF * HD * 2);
  short* W2T   = (short*)alloc((size_t)2 * HD * DFF * 2);
  short* WoutT = (short*)alloc((size_t)OUT_DIM * HD * 2);
  short* dsW1T = (short*)alloc((size_t)OUT_DIM * OUT_DIM * 2);

  // all weight transposes (f32 -> bf16, N x K) in ONE dispatch
  transpose_all<<<17728, 256, 0, stream>>>(W_in, Wqkv, Wo, W1, W2, W_out, ds_W1,
                                           WinT, WqkvT, WoT, W1T, W2T, WoutT, dsW1T);

  // forward
  build_hin<<<MROWS, 256, 0, stream>>>(x, ctx, tmp2);
  gemm_bt<1, short><<<dim3(33, 8), 256, 0, stream>>>(tmp2, WinT, b_in, h, MROWS, 1024, 1024);

  for (int l = 0; l < 2; ++l) {
    gemm_bt<0, short><<<dim3(33, 24), 256, 0, stream>>>(
        h, WqkvT + (size_t)l * 3072 * 1024, bqkv + l * 3072, tmp1, MROWS, 3072, 1024);
    attention_kern<<<dim3(SEQ, NHEAD), 128, 0, stream>>>(tmp1, tmp2);
    gemm_bt<0, short><<<dim3(33, 8), 256, 0, stream>>>(
        tmp2, WoT + (size_t)l * 1024 * 1024, bo + l * 1024, tmp3, MROWS, 1024, 1024);
    add_ln<<<MROWS, 256, 0, stream>>>(h, tmp3, ln1_g + l * 1024, ln1_b + l * 1024, h);
    gemm_bt<1, short><<<dim3(33, 16), 256, 0, stream>>>(
        h, W1T + (size_t)l * 2048 * 1024, b1 + l * 2048, tmp1, MROWS, 2048, 1024);
    gemm_bt<0, short><<<dim3(33, 8), 256, 0, stream>>>(
        tmp1, W2T + (size_t)l * 1024 * 2048, b2 + l * 1024, tmp3, MROWS, 1024, 2048);
    add_ln<<<MROWS, 256, 0, stream>>>(h, tmp3, ln2_g + l * 1024, ln2_b + l * 1024, h);
  }

  gemm_bt<0, float><<<dim3(33, 2), 256, 0, stream>>>(h, WoutT, b_out, outb, MROWS, 256, 1024);

  float* pred = (float*)d_out;
  float* cand_out = (float*)d_out + (size_t)B_ * S_ * OUT_DIM;
  gather_cand<<<4096, 256, 0, stream>>>(outb, indices, KB, pred, cand_out, dbuf);
  gemm_bt<1, short><<<dim3(320, 2), 256, 0, stream>>>(dbuf, dsW1T, ds_b1, t1, NCAND, 256, 256);
  score_reduce<<<NCAND / 4, 256, 0, stream>>>(t1, ds_W2, ds_b2, cand_out);
}